// Round 25
// baseline (99.268 us; speedup 1.0000x reference)
//
#include <hip/hip_runtime.h>
#include <hip/hip_bf16.h>
#include <hip/hip_fp8.h>

typedef __attribute__((ext_vector_type(8))) short short8v;
typedef __attribute__((ext_vector_type(4))) float f32x4;
typedef __attribute__((ext_vector_type(2))) float f32x2;

#define DEVFN __device__ __forceinline__

DEVFN unsigned short f2bf(float x) {
  __hip_bfloat16 h = __float2bfloat16(x);
  return *reinterpret_cast<unsigned short*>(&h);
}

DEVFN float bf2f(unsigned short u) {
  unsigned int x = ((unsigned int)u) << 16;
  float f;
  __builtin_memcpy(&f, &x, 4);
  return f;
}

DEVFN unsigned char f2fp8(float x) {
  __hip_fp8_e4m3 h(x);
  return *reinterpret_cast<unsigned char*>(&h);
}

#if __has_builtin(__builtin_amdgcn_cvt_pk_f32_fp8)
DEVFN void fp8x4_to_f32(unsigned int u, float* out) {
  f32x2 lo = __builtin_amdgcn_cvt_pk_f32_fp8(u, false);
  f32x2 hi = __builtin_amdgcn_cvt_pk_f32_fp8(u, true);
  out[0] = lo[0]; out[1] = lo[1]; out[2] = hi[0]; out[3] = hi[1];
}
#else
DEVFN float fp8_1_to_f32(unsigned int b) {
  const unsigned int s = (b >> 7) & 1, e = (b >> 3) & 15, m = b & 7;
  unsigned int bits = (s << 31) | ((e + 120) << 23) | (m << 20);
  float f;
  __builtin_memcpy(&f, &bits, 4);
  if (e == 0) f = (s ? -1.f : 1.f) * (float)m * 0.001953125f;
  return f;
}
DEVFN void fp8x4_to_f32(unsigned int u, float* out) {
  out[0] = fp8_1_to_f32(u & 0xff);
  out[1] = fp8_1_to_f32((u >> 8) & 0xff);
  out[2] = fp8_1_to_f32((u >> 16) & 0xff);
  out[3] = fp8_1_to_f32((u >> 24) & 0xff);
}
#endif

DEVFN void gload16(const void* g, void* l) {
  __builtin_amdgcn_global_load_lds(
      (const __attribute__((address_space(1))) void*)g,
      (__attribute__((address_space(3))) void*)l, 16, 0, 0);
}

// Weight transpose-casts + q_start only (input casts fused into proj).
__global__ __launch_bounds__(256) void prep(
    const float* __restrict__ Wk, const float* __restrict__ Wv,
    const float* __restrict__ Wq, const float* __restrict__ Wo,
    const float* __restrict__ Wg,
    unsigned short* __restrict__ Btkv, unsigned short* __restrict__ Btq,
    unsigned short* __restrict__ Bto, unsigned short* __restrict__ Btg,
    const int* __restrict__ q_idx, int* __restrict__ q_start, int Q, int E) {
  const int b = blockIdx.x, t = threadIdx.x;
  if (b < 256) {
    const int wi = b >> 6, bb = b & 63;
    const float* W = (wi == 0) ? Wk : (wi == 1) ? Wv : (wi == 2) ? Wq : Wo;
    unsigned short* O = (wi == 0) ? Btkv : (wi == 1) ? (Btkv + 65536)
                     : (wi == 2) ? Btq : Bto;
    for (int id = bb * 256 + t; id < 65536; id += 64 * 256) {
      const int n = id >> 8, k = id & 255;
      O[id] = f2bf(W[k * 256 + n]);
    }
  } else if (b < 272) {
    for (int id = (b - 256) * 256 + t; id < 16384; id += 16 * 256) {
      const int n = id >> 6, k = id & 63;
      Btg[id] = f2bf(Wg[k * 256 + n]);
    }
  } else {
    const int q = (b - 272) * 256 + t;
    if (q <= Q) {
      int lo = 0, hi = E;
      while (lo < hi) { int mid = (lo + hi) >> 1; if (q_idx[mid] < q) lo = mid + 1; else hi = mid; }
      q_start[q] = lo;
    }
  }
}

// ---------- Persistent-A, barrier-free KV GEMM ----------
// One block owns 128 rows x 512 cols. Phase 1: A (fp32) reg-staged + cast
// to bf16 into As[8] K-tiles (64 KB), no compute, implicit-wait chained.
// ONE lgkmcnt(0)+barrier. Phase 2: 4 panels x 8 k-tiles with ZERO barriers:
// B fragments loaded straight into MFMA register layout from global
// (L2-resident, 16 B/lane), A fragments via ds_read_b128 from immutable As.
DEVFN void gemm_kv_persist(const float* __restrict__ A,
                           const unsigned short* __restrict__ Bt,
                           unsigned char* __restrict__ KV,
                           int bid, int nwg,
                           unsigned short (*As)[128 * 32]) {  // 8 buffers
  constexpr int K = 256;
  const int t = threadIdx.x;
  const int wv = t >> 6, l = t & 63;
  const int wr = wv >> 1, wc = wv & 1;
  const int lr = l & 15, lk = l >> 4;

  const int swz = (bid & 7) * (nwg >> 3) + (bid >> 3);
  const int m0 = swz * 128;

  const int arow = t >> 1, ac0 = (t & 1) * 2;
  const float* Afp = A + (size_t)(m0 + arow) * K + ac0 * 8;

  float4 reg0[4], reg1[4];

  auto loadA = [&](float4 (&rg)[4], int k0) {
    const float* p = Afp + k0;
#pragma unroll
    for (int j = 0; j < 4; ++j) rg[j] = *(const float4*)(p + j * 4);
  };
  auto writeA = [&](float4 (&rg)[4], int tile) {
    unsigned short u[16];
#pragma unroll
    for (int j = 0; j < 4; ++j) {
      u[4 * j + 0] = f2bf(rg[j].x); u[4 * j + 1] = f2bf(rg[j].y);
      u[4 * j + 2] = f2bf(rg[j].z); u[4 * j + 3] = f2bf(rg[j].w);
    }
    const int cs0 = ac0 ^ ((arow >> 1) & 3);
    const int cs1 = (ac0 + 1) ^ ((arow >> 1) & 3);
    *(short8v*)&As[tile][arow * 32 + cs0 * 8] = *(short8v*)&u[0];
    *(short8v*)&As[tile][arow * 32 + cs1 * 8] = *(short8v*)&u[8];
  };
  auto loadSlot = [&](int tile) {
    if ((tile & 1) == 0) loadA(reg0, tile * 32);
    else                 loadA(reg1, tile * 32);
  };
  auto writeSlot = [&](int tile) {
    if ((tile & 1) == 0) writeA(reg0, tile);
    else                 writeA(reg1, tile);
  };

  // Phase 1: stage all 8 A K-tiles (depth-2 reg pipeline, implicit waits).
  loadSlot(0);
  loadSlot(1);
#pragma unroll
  for (int tt = 0; tt < 8; ++tt) {
    writeSlot(tt);                  // implicit vmcnt wait on tile tt's loads
    if (tt + 2 < 8) loadSlot(tt + 2);
  }
  asm volatile("s_waitcnt lgkmcnt(0)" ::: "memory");
  __builtin_amdgcn_s_barrier();     // the ONLY barrier
  __builtin_amdgcn_sched_barrier(0);

  // Phase 2: barrier-free sweep. acc over k-tiles per panel.
  f32x4 acc[4][4];
#pragma unroll
  for (int m = 0; m < 4; ++m)
#pragma unroll
    for (int n = 0; n < 4; ++n) acc[m][n] = (f32x4){0.f, 0.f, 0.f, 0.f};

#pragma unroll
  for (int p = 0; p < 4; ++p) {
#pragma unroll
    for (int i = 0; i < 8; ++i) {
      short8v b[4];
#pragma unroll
      for (int n = 0; n < 4; ++n)
        b[n] = *(const short8v*)(Bt +
            (size_t)(p * 128 + wc * 64 + n * 16 + lr) * K + i * 32 + lk * 8);
      short8v a[4];
#pragma unroll
      for (int m = 0; m < 4; ++m) {
        const int row = wr * 64 + m * 16 + lr;
        const int cs = lk ^ ((row >> 1) & 3);
        a[m] = *(const short8v*)&As[i][row * 32 + cs * 8];
      }
#pragma unroll
      for (int m = 0; m < 4; ++m)
#pragma unroll
        for (int n = 0; n < 4; ++n)
          acc[m][n] = __builtin_amdgcn_mfma_f32_16x16x32_bf16(a[m], b[n], acc[m][n], 0, 0, 0);
    }
    // panel epilogue: cols p*128 .. p*128+127 (fp8 out)
#pragma unroll
    for (int m = 0; m < 4; ++m)
#pragma unroll
      for (int n = 0; n < 4; ++n) {
        const f32x4 v = acc[m][n];
        const int col = p * 128 + wc * 64 + n * 16 + lr;
        const int rbase = m0 + wr * 64 + m * 16 + lk * 4;
#pragma unroll
        for (int r = 0; r < 4; ++r)
          KV[(size_t)(rbase + r) * 512 + col] = f2fp8(v[r]);
        acc[m][n] = (f32x4){0.f, 0.f, 0.f, 0.f};
      }
  }
}

// ---------- r19-proven deep-pipelined GEMM body (3 As + 3 Bs buffers) ----
// A fp32 reg-staged depth-2, counted vmcnt; or bf16 via global_load_lds.
// OUT_MODE: 0 = fp32, 1 = bf16 at row*ldc+col.
template <int KT, bool A_F32, int OUT_MODE, bool HAS_BIAS>
DEVFN void gemm_body(const void* __restrict__ Av,
                     const unsigned short* __restrict__ Bt,
                     void* __restrict__ Cv, const float* __restrict__ bias,
                     int ldc, int bid, int gx, int nwg,
                     unsigned short (*As)[128 * 32],
                     unsigned short (*Bs)[128 * 32]) {
  constexpr int K = KT * 32;

  const int t = threadIdx.x;
  const int wv = t >> 6, l = t & 63;
  const int wr = wv >> 1, wc = wv & 1;
  const int lr = l & 15, lk = l >> 4;

  const int swz = (bid & 7) * (nwg >> 3) + (bid >> 3);
  const int n0 = (swz % gx) * 128;
  const int m0 = (swz / gx) * 128;

  f32x4 acc[4][4];
#pragma unroll
  for (int m = 0; m < 4; ++m)
#pragma unroll
    for (int n = 0; n < 4; ++n) acc[m][n] = (f32x4){0.f, 0.f, 0.f, 0.f};

  const int wbase = (t & ~63) * 16;
  const int arow = t >> 1, ac0 = (t & 1) * 2;
  const float* Afp = A_F32 ? ((const float*)Av + (size_t)(m0 + arow) * K + ac0 * 8)
                           : nullptr;
  float4 reg0[4], reg1[4];

  auto loadA = [&](float4 (&rg)[4], int k0) {
    const float* p = Afp + k0;
#pragma unroll
    for (int j = 0; j < 4; ++j) rg[j] = *(const float4*)(p + j * 4);
  };
  auto writeA = [&](float4 (&rg)[4], int buf) {
    unsigned short u[16];
#pragma unroll
    for (int j = 0; j < 4; ++j) {
      u[4 * j + 0] = f2bf(rg[j].x); u[4 * j + 1] = f2bf(rg[j].y);
      u[4 * j + 2] = f2bf(rg[j].z); u[4 * j + 3] = f2bf(rg[j].w);
    }
    const int cs0 = ac0 ^ ((arow >> 1) & 3);
    const int cs1 = (ac0 + 1) ^ ((arow >> 1) & 3);
    *(short8v*)&As[buf][arow * 32 + cs0 * 8] = *(short8v*)&u[0];
    *(short8v*)&As[buf][arow * 32 + cs1 * 8] = *(short8v*)&u[8];
  };
  auto stageA_lds = [&](int buf, int k0) {
    const unsigned short* Ab = (const unsigned short*)Av;
#pragma unroll
    for (int s = 0; s < 2; ++s) {
      const int cidx = s * 256 + t;
      const int row = cidx >> 2, c = cidx & 3;
      const int cs = c ^ ((row >> 1) & 3);
      gload16(Ab + (size_t)(m0 + row) * K + k0 + cs * 8,
              (char*)&As[buf][0] + (size_t)s * 4096 + wbase);
    }
  };
  auto stageB = [&](int buf, int k0) {
#pragma unroll
    for (int s = 0; s < 2; ++s) {
      const int cidx = s * 256 + t;
      const int row = cidx >> 2, c = cidx & 3;
      const int cs = c ^ ((row >> 1) & 3);
      gload16(Bt + (size_t)(n0 + row) * K + k0 + cs * 8,
              (char*)&Bs[buf][0] + (size_t)s * 4096 + wbase);
    }
  };

  auto compute = [&](int buf) {
    short8v a[4], b[4];
#pragma unroll
    for (int m = 0; m < 4; ++m) {
      const int row = wr * 64 + m * 16 + lr;
      const int cs = lk ^ ((row >> 1) & 3);
      a[m] = *(const short8v*)&As[buf][row * 32 + cs * 8];
    }
#pragma unroll
    for (int n = 0; n < 4; ++n) {
      const int row = wc * 64 + n * 16 + lr;
      const int cs = lk ^ ((row >> 1) & 3);
      b[n] = *(const short8v*)&Bs[buf][row * 32 + cs * 8];
    }
#pragma unroll
    for (int m = 0; m < 4; ++m)
#pragma unroll
      for (int n = 0; n < 4; ++n)
        acc[m][n] = __builtin_amdgcn_mfma_f32_16x16x32_bf16(a[m], b[n], acc[m][n], 0, 0, 0);
  };

  stageB(0, 0);
  if (KT > 1) stageB(1, 32);
  if (A_F32) {
    loadA(reg0, 0);
    if (KT > 1) loadA(reg1, 32);
    writeA(reg0, 0);
  } else {
    stageA_lds(0, 0);
    if (KT > 1) stageA_lds(1, 32);
  }

#pragma unroll
  for (int tt = 0; tt < KT; ++tt) {
    __builtin_amdgcn_s_barrier();
    __builtin_amdgcn_sched_barrier(0);
    if (A_F32) {
      if (tt + 2 < KT) {
        if (((tt + 2) & 1) == 0) loadA(reg0, (tt + 2) * 32);
        else                     loadA(reg1, (tt + 2) * 32);
        stageB((tt + 2) % 3, (tt + 2) * 32);
      }
      if (tt + 1 < KT) {
        if (((tt + 1) & 1) == 0) writeA(reg0, (tt + 1) % 3);
        else                     writeA(reg1, (tt + 1) % 3);
      }
      if (tt < KT - 2)       asm volatile("s_waitcnt vmcnt(8) lgkmcnt(0)" ::: "memory");
      else if (tt == KT - 2) asm volatile("s_waitcnt vmcnt(2) lgkmcnt(0)" ::: "memory");
      else                   asm volatile("s_waitcnt vmcnt(0) lgkmcnt(0)" ::: "memory");
    } else {
      if (tt + 2 < KT) {
        stageA_lds((tt + 2) % 3, (tt + 2) * 32);
        stageB((tt + 2) % 3, (tt + 2) * 32);
      }
      const int rem = (tt + 2 < KT ? tt + 2 : KT - 1) - tt;
      if (rem >= 2)      asm volatile("s_waitcnt vmcnt(8)" ::: "memory");
      else if (rem == 1) asm volatile("s_waitcnt vmcnt(4)" ::: "memory");
      else               asm volatile("s_waitcnt vmcnt(0)" ::: "memory");
    }
    __builtin_amdgcn_s_barrier();
    __builtin_amdgcn_sched_barrier(0);
    compute(tt % 3);
  }

#pragma unroll
  for (int m = 0; m < 4; ++m)
#pragma unroll
    for (int n = 0; n < 4; ++n) {
      const f32x4 v = acc[m][n];
      const int col = n0 + wc * 64 + n * 16 + lr;
      const int rbase = m0 + wr * 64 + m * 16 + lk * 4;
      float bv = 0.f;
      if (HAS_BIAS) bv = bias[col];
#pragma unroll
      for (int r = 0; r < 4; ++r) {
        const float val = v[r] + bv;
        if (OUT_MODE == 0) {
          ((float*)Cv)[(size_t)(rbase + r) * ldc + col] = val;
        } else {
          ((unsigned short*)Cv)[(size_t)(rbase + r) * ldc + col] = f2bf(val);
        }
      }
    }
}

// Megakernel: blocks [0,512): KV persistent-A barrier-free (fp8 K|V out);
// [512,640): Qf (r19 body); [640,768): Gf (r19 body, K=64).
// Shared LDS pool: 64 KB (KV: As[8]; Qf/Gf: As[3]+Bs[3] carved).
__global__ __launch_bounds__(256) void proj(
    const float* __restrict__ support, const float* __restrict__ query,
    const float* __restrict__ geo,
    const unsigned short* __restrict__ Btkv, const unsigned short* __restrict__ Btq,
    const unsigned short* __restrict__ Btg,
    unsigned char* __restrict__ KV, unsigned short* __restrict__ Qf,
    unsigned short* __restrict__ Gf) {
  __shared__ unsigned short LDSU[32768];  // 64 KB
  const int b = blockIdx.x;
  if (b < 512) {
    gemm_kv_persist(support, Btkv, KV, b, 512,
                    (unsigned short (*)[128 * 32])&LDSU[0]);
  } else if (b < 640) {
    gemm_body<8, true, 1, false>(query, Btq, Qf, nullptr, 256, b - 512, 2, 128,
                                 (unsigned short (*)[128 * 32])&LDSU[0],
                                 (unsigned short (*)[128 * 32])&LDSU[12288]);
  } else {
    gemm_body<2, true, 1, false>(geo, Btg, Gf, nullptr, 256, b - 640, 2, 128,
                                 (unsigned short (*)[128 * 32])&LDSU[0],
                                 (unsigned short (*)[128 * 32])&LDSU[12288]);
  }
}

// Final: out = Opre(bf16) @ Wo^T + bo (fp32 out).
__global__ __launch_bounds__(256) void gemm_final(
    const unsigned short* __restrict__ A, const unsigned short* __restrict__ Bt,
    void* __restrict__ C, const float* __restrict__ bias) {
  __shared__ unsigned short As[3][128 * 32];
  __shared__ unsigned short Bs[3][128 * 32];
  gemm_body<8, false, 0, true>(A, Bt, C, bias, 256, blockIdx.x, 2, 128, As, Bs);
}

// One block (256 thr) per query; 8 edge streams; 32 lanes per edge.
// KV row (512 B) = K fp8 (256 B) | V fp8 (256 B). Depth-2 rolling prefetch.
// No online max (exact; scores bounded).
__global__ __launch_bounds__(256) void edge_attn(
    const int* __restrict__ s_idx, const int* __restrict__ q_start,
    const unsigned char* __restrict__ KVb, const unsigned short* __restrict__ Qf,
    const unsigned short* __restrict__ Gf, unsigned short* __restrict__ out_pre,
    const float* __restrict__ log_tau) {
  const int q = blockIdx.x;
  const int t = threadIdx.x;
  const int w = t >> 6;
  const int lane = t & 63;
  const int stream = w * 2 + (lane >> 5);
  const int sl = lane & 31;
  const int start = q_start[q], end = q_start[q + 1];

  const float tau = __expf(log_tau[0]);
  const float rs = 1.0f / (5.656854249492381f * tau);

  float qv[8];
  {
    uint4 qw = *(const uint4*)(Qf + (size_t)q * 256 + sl * 8);
    const unsigned int ws_[4] = {qw.x, qw.y, qw.z, qw.w};
#pragma unroll
    for (int j = 0; j < 4; ++j) {
      qv[2 * j]     = bf2f((unsigned short)(ws_[j] & 0xffffu)) * rs;
      qv[2 * j + 1] = bf2f((unsigned short)(ws_[j] >> 16)) * rs;
    }
  }

  float o[8];
#pragma unroll
  for (int j = 0; j < 8; ++j) o[j] = 0.f;
  float lsum_p = 0.f;

  __shared__ int sseg[1024];

  for (int cb = start; cb < end; cb += 1024) {
    const int nb = min(1024, end - cb);
    __syncthreads();
    for (int jj = t; jj < nb; jj += 256) sseg[jj] = s_idx[cb + jj];
    __syncthreads();

    int j = stream;
    uint2 kc = {}, kn = {}, vc = {}, vn = {};
    if (j < nb) {
      const unsigned char* bp = KVb + (size_t)sseg[j] * 512;
      kc = *(const uint2*)(bp + sl * 8);
      vc = *(const uint2*)(bp + 256 + sl * 8);
    }
    if (j + 8 < nb) {
      const unsigned char* bp = KVb + (size_t)sseg[j + 8] * 512;
      kn = *(const uint2*)(bp + sl * 8);
      vn = *(const uint2*)(bp + 256 + sl * 8);
    }
    while (j < nb) {
      const int j2 = j + 16;
      uint2 k2 = {}, v2 = {};
      if (j2 < nb) {
        const unsigned char* bp = KVb + (size_t)sseg[j2] * 512;
        k2 = *(const uint2*)(bp + sl * 8);
        v2 = *(const uint2*)(bp + 256 + sl * 8);
      }
      float kf[8];
      fp8x4_to_f32(kc.x, kf);
      fp8x4_to_f32(kc.y, kf + 4);
      float p = 0.f;
#pragma unroll
      for (int jj = 0; jj < 8; ++jj) p = fmaf(qv[jj], kf[jj], p);
      p += __shfl_xor(p, 1);
      p += __shfl_xor(p, 2);
      const float ew = __expf(p);
      lsum_p += ew;
      float vf[8];
      fp8x4_to_f32(vc.x, vf);
      fp8x4_to_f32(vc.y, vf + 4);
#pragma unroll
      for (int jj = 0; jj < 8; ++jj) o[jj] = fmaf(ew, vf[jj], o[jj]);
      j += 8;
      kc = kn; vc = vn;
      kn = k2; vn = v2;
    }
  }

  __shared__ float o_sh[8][256];
  __shared__ float l_sh[8][8];
  *(float4*)&o_sh[stream][sl * 8]     = (float4){o[0], o[1], o[2], o[3]};
  *(float4*)&o_sh[stream][sl * 8 + 4] = (float4){o[4], o[5], o[6], o[7]};
  if ((sl & 3) == 0) l_sh[stream][sl >> 2] = lsum_p;
  __syncthreads();

  float osum = 0.f, lsum = 0.f;
  const int h = t >> 5;
#pragma unroll
  for (int s = 0; s < 8; ++s) {
    osum += o_sh[s][t];
    lsum += l_sh[s][h];
  }
  const float inv = 1.0f / fmaxf(lsum, 1e-8f);
  float res = 0.f;
  if (end > start) res = osum * inv + (lsum * inv) * bf2f(Gf[(size_t)q * 256 + t]);
  out_pre[(size_t)q * 256 + t] = f2bf(res);
}

extern "C" void kernel_launch(void* const* d_in, const int* in_sizes, int n_in,
                              void* d_out, int out_size, void* d_ws, size_t ws_size,
                              hipStream_t stream) {
  const float* query   = (const float*)d_in[0];
  const float* support = (const float*)d_in[1];
  const float* geo     = (const float*)d_in[2];
  const int*   q_idx   = (const int*)d_in[3];
  const int*   s_idx   = (const int*)d_in[4];
  const float* Wq      = (const float*)d_in[6];
  const float* Wk      = (const float*)d_in[7];
  const float* Wv      = (const float*)d_in[8];
  const float* Wg      = (const float*)d_in[9];
  const float* Wo      = (const float*)d_in[10];
  const float* bo      = (const float*)d_in[11];
  const float* log_tau = (const float*)d_in[12];

  const int D = 256;
  const int Q = in_sizes[0] / D;   // 8192
  const int N = in_sizes[1] / D;   // 65536
  const int E = in_sizes[3];       // 262144

  unsigned char* wsb = (unsigned char*)d_ws;
  unsigned char*  KV   = wsb;                                       // [N][512] fp8 K|V
  unsigned short* Qf   = (unsigned short*)(wsb + (size_t)N * 512);  // [Q][256]
  unsigned short* Gf   = Qf   + (size_t)Q * 256;   // [Q][256]
  unsigned short* Opre = Gf   + (size_t)Q * 256;   // [Q][256]
  unsigned short* Btkv = Opre + (size_t)Q * 256;   // [512][256] = [Wk^T; Wv^T]
  unsigned short* Btq  = Btkv + 512 * 256;         // [256][256]
  unsigned short* Btg  = Btq  + 256 * 256;         // [256][64]
  unsigned short* Bto  = Btg  + 256 * 64;          // [256][256]
  int* q_start = (int*)(Bto + 256 * 256);          // [Q+1]

  dim3 blk(256);

  prep<<<dim3(305), blk, 0, stream>>>(Wk, Wv, Wq, Wo, Wg,
                                      Btkv, Btq, Bto, Btg, q_idx, q_start, Q, E);

  // KV (persistent-A, barrier-free) + Qf + Gf projections in one dispatch
  proj<<<dim3(768), blk, 0, stream>>>(support, query, geo, Btkv, Btq, Btg,
                                      KV, Qf, Gf);

  edge_attn<<<dim3(Q), blk, 0, stream>>>(s_idx, q_start, KV,
                                         Qf, Gf, Opre, log_tau);

  gemm_final<<<dim3(128), blk, 0, stream>>>(Opre, Bto, d_out, bo);
}

// Round 26
// 75.842 us; speedup vs baseline: 1.3089x; 1.3089x over previous
//
#include <hip/hip_runtime.h>
#include <hip/hip_bf16.h>
#include <hip/hip_fp8.h>

typedef __attribute__((ext_vector_type(8))) short short8v;
typedef __attribute__((ext_vector_type(4))) float f32x4;
typedef __attribute__((ext_vector_type(2))) float f32x2;

#define DEVFN __device__ __forceinline__

DEVFN unsigned short f2bf(float x) {
  __hip_bfloat16 h = __float2bfloat16(x);
  return *reinterpret_cast<unsigned short*>(&h);
}

DEVFN float bf2f(unsigned short u) {
  unsigned int x = ((unsigned int)u) << 16;
  float f;
  __builtin_memcpy(&f, &x, 4);
  return f;
}

DEVFN unsigned char f2fp8(float x) {
  __hip_fp8_e4m3 h(x);
  return *reinterpret_cast<unsigned char*>(&h);
}

#if __has_builtin(__builtin_amdgcn_cvt_pk_f32_fp8)
DEVFN void fp8x4_to_f32(unsigned int u, float* out) {
  f32x2 lo = __builtin_amdgcn_cvt_pk_f32_fp8(u, false);
  f32x2 hi = __builtin_amdgcn_cvt_pk_f32_fp8(u, true);
  out[0] = lo[0]; out[1] = lo[1]; out[2] = hi[0]; out[3] = hi[1];
}
#else
DEVFN float fp8_1_to_f32(unsigned int b) {
  const unsigned int s = (b >> 7) & 1, e = (b >> 3) & 15, m = b & 7;
  unsigned int bits = (s << 31) | ((e + 120) << 23) | (m << 20);
  float f;
  __builtin_memcpy(&f, &bits, 4);
  if (e == 0) f = (s ? -1.f : 1.f) * (float)m * 0.001953125f;
  return f;
}
DEVFN void fp8x4_to_f32(unsigned int u, float* out) {
  out[0] = fp8_1_to_f32(u & 0xff);
  out[1] = fp8_1_to_f32((u >> 8) & 0xff);
  out[2] = fp8_1_to_f32((u >> 16) & 0xff);
  out[3] = fp8_1_to_f32((u >> 24) & 0xff);
}
#endif

DEVFN void gload16(const void* g, void* l) {
  __builtin_amdgcn_global_load_lds(
      (const __attribute__((address_space(1))) void*)g,
      (__attribute__((address_space(3))) void*)l, 16, 0, 0);
}

// Weight transpose-casts + q_start only (input casts fused into proj).
__global__ __launch_bounds__(256) void prep(
    const float* __restrict__ Wk, const float* __restrict__ Wv,
    const float* __restrict__ Wq, const float* __restrict__ Wo,
    const float* __restrict__ Wg,
    unsigned short* __restrict__ Btkv, unsigned short* __restrict__ Btq,
    unsigned short* __restrict__ Bto, unsigned short* __restrict__ Btg,
    const int* __restrict__ q_idx, int* __restrict__ q_start, int Q, int E) {
  const int b = blockIdx.x, t = threadIdx.x;
  if (b < 256) {
    const int wi = b >> 6, bb = b & 63;
    const float* W = (wi == 0) ? Wk : (wi == 1) ? Wv : (wi == 2) ? Wq : Wo;
    unsigned short* O = (wi == 0) ? Btkv : (wi == 1) ? (Btkv + 65536)
                     : (wi == 2) ? Btq : Bto;
    for (int id = bb * 256 + t; id < 65536; id += 64 * 256) {
      const int n = id >> 8, k = id & 255;
      O[id] = f2bf(W[k * 256 + n]);
    }
  } else if (b < 272) {
    for (int id = (b - 256) * 256 + t; id < 16384; id += 16 * 256) {
      const int n = id >> 6, k = id & 63;
      Btg[id] = f2bf(Wg[k * 256 + n]);
    }
  } else {
    const int q = (b - 272) * 256 + t;
    if (q <= Q) {
      int lo = 0, hi = E;
      while (lo < hi) { int mid = (lo + hi) >> 1; if (q_idx[mid] < q) lo = mid + 1; else hi = mid; }
      q_start[q] = lo;
    }
  }
}

// ---------- Persistent-A KV GEMM body ----------
// One block owns 128 rows x all 512 cols. A (fp32) is reg-staged + cast to
// bf16 LDS ONCE (As[8] K-tiles, filled during panel 0); panels 1-3 iterate
// with only B staging (L2-resident). Bs[2] double-buffer, depth-1, counted
// vmcnt(2) (never 0 mid-loop). 2 barriers/iter; stageB ordered BEFORE loadA
// so writeA's implicit vmcnt drains B(i) on heavy iters.
DEVFN void gemm_kv_persist(const float* __restrict__ A,
                           const unsigned short* __restrict__ Bt,
                           unsigned char* __restrict__ KV,
                           int bid, int nwg,
                           unsigned short (*As)[128 * 32],   // 8 buffers
                           unsigned short (*Bs)[128 * 32]) { // 2 buffers
  constexpr int K = 256;
  const int t = threadIdx.x;
  const int wv = t >> 6, l = t & 63;
  const int wr = wv >> 1, wc = wv & 1;
  const int lr = l & 15, lk = l >> 4;

  const int swz = (bid & 7) * (nwg >> 3) + (bid >> 3);
  const int m0 = swz * 128;

  const int wbase = (t & ~63) * 16;
  const int arow = t >> 1, ac0 = (t & 1) * 2;
  const float* Afp = A + (size_t)(m0 + arow) * K + ac0 * 8;

  f32x4 acc[4][4];
#pragma unroll
  for (int m = 0; m < 4; ++m)
#pragma unroll
    for (int n = 0; n < 4; ++n) acc[m][n] = (f32x4){0.f, 0.f, 0.f, 0.f};

  float4 reg0[4], reg1[4];

  auto loadA = [&](float4 (&rg)[4], int k0) {
    const float* p = Afp + k0;
#pragma unroll
    for (int j = 0; j < 4; ++j) rg[j] = *(const float4*)(p + j * 4);
  };
  auto writeA = [&](float4 (&rg)[4], int tile) {
    unsigned short u[16];
#pragma unroll
    for (int j = 0; j < 4; ++j) {
      u[4 * j + 0] = f2bf(rg[j].x); u[4 * j + 1] = f2bf(rg[j].y);
      u[4 * j + 2] = f2bf(rg[j].z); u[4 * j + 3] = f2bf(rg[j].w);
    }
    const int cs0 = ac0 ^ ((arow >> 1) & 3);
    const int cs1 = (ac0 + 1) ^ ((arow >> 1) & 3);
    *(short8v*)&As[tile][arow * 32 + cs0 * 8] = *(short8v*)&u[0];
    *(short8v*)&As[tile][arow * 32 + cs1 * 8] = *(short8v*)&u[8];
  };
  auto loadSlot = [&](int tile) {
    if ((tile & 1) == 0) loadA(reg0, tile * 32);
    else                 loadA(reg1, tile * 32);
  };
  auto writeSlot = [&](int tile) {
    if ((tile & 1) == 0) writeA(reg0, tile);
    else                 writeA(reg1, tile);
  };
  auto stageB = [&](int buf, int p, int k0) {
#pragma unroll
    for (int s = 0; s < 2; ++s) {
      const int cidx = s * 256 + t;
      const int row = cidx >> 2, c = cidx & 3;
      const int cs = c ^ ((row >> 1) & 3);
      gload16(Bt + (size_t)(p * 128 + row) * K + k0 + cs * 8,
              (char*)&Bs[buf][0] + (size_t)s * 4096 + wbase);
    }
  };
  auto compute = [&](int atile, int bbuf) {
    short8v a[4], b[4];
#pragma unroll
    for (int m = 0; m < 4; ++m) {
      const int row = wr * 64 + m * 16 + lr;
      const int cs = lk ^ ((row >> 1) & 3);
      a[m] = *(const short8v*)&As[atile][row * 32 + cs * 8];
    }
#pragma unroll
    for (int n = 0; n < 4; ++n) {
      const int row = wc * 64 + n * 16 + lr;
      const int cs = lk ^ ((row >> 1) & 3);
      b[n] = *(const short8v*)&Bs[bbuf][row * 32 + cs * 8];
    }
#pragma unroll
    for (int m = 0; m < 4; ++m)
#pragma unroll
      for (int n = 0; n < 4; ++n)
        acc[m][n] = __builtin_amdgcn_mfma_f32_16x16x32_bf16(a[m], b[n], acc[m][n], 0, 0, 0);
  };

  // prologue: B(0) first (so writeA's implicit A-wait also drains it);
  // A tiles 0,1 -> regs; As[0] written.
  stageB(0, 0, 0);
  loadSlot(0);
  loadSlot(1);
  writeSlot(0);                       // implicit wait drains A(0) and B(0)
  asm volatile("s_waitcnt lgkmcnt(0)" ::: "memory");
  __builtin_amdgcn_s_barrier();
  __builtin_amdgcn_sched_barrier(0);

#pragma unroll
  for (int i = 0; i < 32; ++i) {
    if (i > 0) {                      // B1: compute(i-1) reads complete
      __builtin_amdgcn_s_barrier();
      __builtin_amdgcn_sched_barrier(0);
    }
    if (i < 8) {
      if (i + 1 < 8) writeSlot(i + 1);            // implicit wait drains B(i)
      stageB((i + 1) & 1, (i + 1) >> 3, ((i + 1) & 7) * 32);
      if (i + 2 < 8) loadSlot(i + 2);             // issued AFTER stageB
      if (i == 7) asm volatile("s_waitcnt vmcnt(2) lgkmcnt(0)" ::: "memory");
      else        asm volatile("s_waitcnt lgkmcnt(0)" ::: "memory");
    } else {
      if (i + 1 < 32) {
        stageB((i + 1) & 1, (i + 1) >> 3, ((i + 1) & 7) * 32);
        asm volatile("s_waitcnt vmcnt(2)" ::: "memory");
      } else {
        asm volatile("s_waitcnt vmcnt(0)" ::: "memory");
      }
    }
    __builtin_amdgcn_s_barrier();     // B2: tile i data visible to all
    __builtin_amdgcn_sched_barrier(0);
    compute(i & 7, i & 1);
    if ((i & 7) == 7) {               // panel epilogue: cols p*128..p*128+127
      const int p = i >> 3;
#pragma unroll
      for (int m = 0; m < 4; ++m)
#pragma unroll
        for (int n = 0; n < 4; ++n) {
          const f32x4 v = acc[m][n];
          const int col = p * 128 + wc * 64 + n * 16 + lr;
          const int rbase = m0 + wr * 64 + m * 16 + lk * 4;
#pragma unroll
          for (int r = 0; r < 4; ++r)
            KV[(size_t)(rbase + r) * 512 + col] = f2fp8(v[r]);
          acc[m][n] = (f32x4){0.f, 0.f, 0.f, 0.f};
        }
    }
  }
}

// ---------- r19-proven deep-pipelined GEMM body (3 As + 3 Bs buffers) ----
// A fp32 reg-staged depth-2, counted vmcnt; or bf16 via global_load_lds.
// OUT_MODE: 0 = fp32, 1 = bf16 at row*ldc+col.
template <int KT, bool A_F32, int OUT_MODE, bool HAS_BIAS>
DEVFN void gemm_body(const void* __restrict__ Av,
                     const unsigned short* __restrict__ Bt,
                     void* __restrict__ Cv, const float* __restrict__ bias,
                     int ldc, int bid, int gx, int nwg,
                     unsigned short (*As)[128 * 32],
                     unsigned short (*Bs)[128 * 32]) {
  constexpr int K = KT * 32;

  const int t = threadIdx.x;
  const int wv = t >> 6, l = t & 63;
  const int wr = wv >> 1, wc = wv & 1;
  const int lr = l & 15, lk = l >> 4;

  const int swz = (bid & 7) * (nwg >> 3) + (bid >> 3);
  const int n0 = (swz % gx) * 128;
  const int m0 = (swz / gx) * 128;

  f32x4 acc[4][4];
#pragma unroll
  for (int m = 0; m < 4; ++m)
#pragma unroll
    for (int n = 0; n < 4; ++n) acc[m][n] = (f32x4){0.f, 0.f, 0.f, 0.f};

  const int wbase = (t & ~63) * 16;
  const int arow = t >> 1, ac0 = (t & 1) * 2;
  const float* Afp = A_F32 ? ((const float*)Av + (size_t)(m0 + arow) * K + ac0 * 8)
                           : nullptr;
  float4 reg0[4], reg1[4];

  auto loadA = [&](float4 (&rg)[4], int k0) {
    const float* p = Afp + k0;
#pragma unroll
    for (int j = 0; j < 4; ++j) rg[j] = *(const float4*)(p + j * 4);
  };
  auto writeA = [&](float4 (&rg)[4], int buf) {
    unsigned short u[16];
#pragma unroll
    for (int j = 0; j < 4; ++j) {
      u[4 * j + 0] = f2bf(rg[j].x); u[4 * j + 1] = f2bf(rg[j].y);
      u[4 * j + 2] = f2bf(rg[j].z); u[4 * j + 3] = f2bf(rg[j].w);
    }
    const int cs0 = ac0 ^ ((arow >> 1) & 3);
    const int cs1 = (ac0 + 1) ^ ((arow >> 1) & 3);
    *(short8v*)&As[buf][arow * 32 + cs0 * 8] = *(short8v*)&u[0];
    *(short8v*)&As[buf][arow * 32 + cs1 * 8] = *(short8v*)&u[8];
  };
  auto stageA_lds = [&](int buf, int k0) {
    const unsigned short* Ab = (const unsigned short*)Av;
#pragma unroll
    for (int s = 0; s < 2; ++s) {
      const int cidx = s * 256 + t;
      const int row = cidx >> 2, c = cidx & 3;
      const int cs = c ^ ((row >> 1) & 3);
      gload16(Ab + (size_t)(m0 + row) * K + k0 + cs * 8,
              (char*)&As[buf][0] + (size_t)s * 4096 + wbase);
    }
  };
  auto stageB = [&](int buf, int k0) {
#pragma unroll
    for (int s = 0; s < 2; ++s) {
      const int cidx = s * 256 + t;
      const int row = cidx >> 2, c = cidx & 3;
      const int cs = c ^ ((row >> 1) & 3);
      gload16(Bt + (size_t)(n0 + row) * K + k0 + cs * 8,
              (char*)&Bs[buf][0] + (size_t)s * 4096 + wbase);
    }
  };

  auto compute = [&](int buf) {
    short8v a[4], b[4];
#pragma unroll
    for (int m = 0; m < 4; ++m) {
      const int row = wr * 64 + m * 16 + lr;
      const int cs = lk ^ ((row >> 1) & 3);
      a[m] = *(const short8v*)&As[buf][row * 32 + cs * 8];
    }
#pragma unroll
    for (int n = 0; n < 4; ++n) {
      const int row = wc * 64 + n * 16 + lr;
      const int cs = lk ^ ((row >> 1) & 3);
      b[n] = *(const short8v*)&Bs[buf][row * 32 + cs * 8];
    }
#pragma unroll
    for (int m = 0; m < 4; ++m)
#pragma unroll
      for (int n = 0; n < 4; ++n)
        acc[m][n] = __builtin_amdgcn_mfma_f32_16x16x32_bf16(a[m], b[n], acc[m][n], 0, 0, 0);
  };

  stageB(0, 0);
  if (KT > 1) stageB(1, 32);
  if (A_F32) {
    loadA(reg0, 0);
    if (KT > 1) loadA(reg1, 32);
    writeA(reg0, 0);
  } else {
    stageA_lds(0, 0);
    if (KT > 1) stageA_lds(1, 32);
  }

#pragma unroll
  for (int tt = 0; tt < KT; ++tt) {
    __builtin_amdgcn_s_barrier();
    __builtin_amdgcn_sched_barrier(0);
    if (A_F32) {
      if (tt + 2 < KT) {
        if (((tt + 2) & 1) == 0) loadA(reg0, (tt + 2) * 32);
        else                     loadA(reg1, (tt + 2) * 32);
        stageB((tt + 2) % 3, (tt + 2) * 32);
      }
      if (tt + 1 < KT) {
        if (((tt + 1) & 1) == 0) writeA(reg0, (tt + 1) % 3);
        else                     writeA(reg1, (tt + 1) % 3);
      }
      if (tt < KT - 2)       asm volatile("s_waitcnt vmcnt(8) lgkmcnt(0)" ::: "memory");
      else if (tt == KT - 2) asm volatile("s_waitcnt vmcnt(2) lgkmcnt(0)" ::: "memory");
      else                   asm volatile("s_waitcnt vmcnt(0) lgkmcnt(0)" ::: "memory");
    } else {
      if (tt + 2 < KT) {
        stageA_lds((tt + 2) % 3, (tt + 2) * 32);
        stageB((tt + 2) % 3, (tt + 2) * 32);
      }
      const int rem = (tt + 2 < KT ? tt + 2 : KT - 1) - tt;
      if (rem >= 2)      asm volatile("s_waitcnt vmcnt(8)" ::: "memory");
      else if (rem == 1) asm volatile("s_waitcnt vmcnt(4)" ::: "memory");
      else               asm volatile("s_waitcnt vmcnt(0)" ::: "memory");
    }
    __builtin_amdgcn_s_barrier();
    __builtin_amdgcn_sched_barrier(0);
    compute(tt % 3);
  }

#pragma unroll
  for (int m = 0; m < 4; ++m)
#pragma unroll
    for (int n = 0; n < 4; ++n) {
      const f32x4 v = acc[m][n];
      const int col = n0 + wc * 64 + n * 16 + lr;
      const int rbase = m0 + wr * 64 + m * 16 + lk * 4;
      float bv = 0.f;
      if (HAS_BIAS) bv = bias[col];
#pragma unroll
      for (int r = 0; r < 4; ++r) {
        const float val = v[r] + bv;
        if (OUT_MODE == 0) {
          ((float*)Cv)[(size_t)(rbase + r) * ldc + col] = val;
        } else {
          ((unsigned short*)Cv)[(size_t)(rbase + r) * ldc + col] = f2bf(val);
        }
      }
    }
}

// Megakernel: blocks [0,512): KV persistent-A (fp8 K|V out, 512 B rows);
// [512,640): Qf (r19 body); [640,768): Gf (r19 body, K=64).
// Shared LDS pool: 80 KB (KV: As[8]+Bs[2]; Qf/Gf: As[3]+Bs[3] carved).
__global__ __launch_bounds__(256) void proj(
    const float* __restrict__ support, const float* __restrict__ query,
    const float* __restrict__ geo,
    const unsigned short* __restrict__ Btkv, const unsigned short* __restrict__ Btq,
    const unsigned short* __restrict__ Btg,
    unsigned char* __restrict__ KV, unsigned short* __restrict__ Qf,
    unsigned short* __restrict__ Gf) {
  __shared__ unsigned short LDSU[40960];  // 80 KB
  const int b = blockIdx.x;
  if (b < 512) {
    gemm_kv_persist(support, Btkv, KV, b, 512,
                    (unsigned short (*)[128 * 32])&LDSU[0],
                    (unsigned short (*)[128 * 32])&LDSU[32768]);
  } else if (b < 640) {
    gemm_body<8, true, 1, false>(query, Btq, Qf, nullptr, 256, b - 512, 2, 128,
                                 (unsigned short (*)[128 * 32])&LDSU[0],
                                 (unsigned short (*)[128 * 32])&LDSU[12288]);
  } else {
    gemm_body<2, true, 1, false>(geo, Btg, Gf, nullptr, 256, b - 640, 2, 128,
                                 (unsigned short (*)[128 * 32])&LDSU[0],
                                 (unsigned short (*)[128 * 32])&LDSU[12288]);
  }
}

// Final: out = Opre(bf16) @ Wo^T + bo (fp32 out).
__global__ __launch_bounds__(256) void gemm_final(
    const unsigned short* __restrict__ A, const unsigned short* __restrict__ Bt,
    void* __restrict__ C, const float* __restrict__ bias) {
  __shared__ unsigned short As[3][128 * 32];
  __shared__ unsigned short Bs[3][128 * 32];
  gemm_body<8, false, 0, true>(A, Bt, C, bias, 256, blockIdx.x, 2, 128, As, Bs);
}

// One block (256 thr) per query; 8 edge streams; 32 lanes per edge.
// KV row (512 B) = K fp8 (256 B) | V fp8 (256 B). Depth-2 rolling prefetch.
// No online max (exact; scores bounded).
__global__ __launch_bounds__(256) void edge_attn(
    const int* __restrict__ s_idx, const int* __restrict__ q_start,
    const unsigned char* __restrict__ KVb, const unsigned short* __restrict__ Qf,
    const unsigned short* __restrict__ Gf, unsigned short* __restrict__ out_pre,
    const float* __restrict__ log_tau) {
  const int q = blockIdx.x;
  const int t = threadIdx.x;
  const int w = t >> 6;
  const int lane = t & 63;
  const int stream = w * 2 + (lane >> 5);
  const int sl = lane & 31;
  const int start = q_start[q], end = q_start[q + 1];

  const float tau = __expf(log_tau[0]);
  const float rs = 1.0f / (5.656854249492381f * tau);

  float qv[8];
  {
    uint4 qw = *(const uint4*)(Qf + (size_t)q * 256 + sl * 8);
    const unsigned int ws_[4] = {qw.x, qw.y, qw.z, qw.w};
#pragma unroll
    for (int j = 0; j < 4; ++j) {
      qv[2 * j]     = bf2f((unsigned short)(ws_[j] & 0xffffu)) * rs;
      qv[2 * j + 1] = bf2f((unsigned short)(ws_[j] >> 16)) * rs;
    }
  }

  float o[8];
#pragma unroll
  for (int j = 0; j < 8; ++j) o[j] = 0.f;
  float lsum_p = 0.f;

  __shared__ int sseg[1024];

  for (int cb = start; cb < end; cb += 1024) {
    const int nb = min(1024, end - cb);
    __syncthreads();
    for (int jj = t; jj < nb; jj += 256) sseg[jj] = s_idx[cb + jj];
    __syncthreads();

    int j = stream;
    uint2 kc = {}, kn = {}, vc = {}, vn = {};
    if (j < nb) {
      const unsigned char* bp = KVb + (size_t)sseg[j] * 512;
      kc = *(const uint2*)(bp + sl * 8);
      vc = *(const uint2*)(bp + 256 + sl * 8);
    }
    if (j + 8 < nb) {
      const unsigned char* bp = KVb + (size_t)sseg[j + 8] * 512;
      kn = *(const uint2*)(bp + sl * 8);
      vn = *(const uint2*)(bp + 256 + sl * 8);
    }
    while (j < nb) {
      const int j2 = j + 16;
      uint2 k2 = {}, v2 = {};
      if (j2 < nb) {
        const unsigned char* bp = KVb + (size_t)sseg[j2] * 512;
        k2 = *(const uint2*)(bp + sl * 8);
        v2 = *(const uint2*)(bp + 256 + sl * 8);
      }
      float kf[8];
      fp8x4_to_f32(kc.x, kf);
      fp8x4_to_f32(kc.y, kf + 4);
      float p = 0.f;
#pragma unroll
      for (int jj = 0; jj < 8; ++jj) p = fmaf(qv[jj], kf[jj], p);
      p += __shfl_xor(p, 1);
      p += __shfl_xor(p, 2);
      const float ew = __expf(p);
      lsum_p += ew;
      float vf[8];
      fp8x4_to_f32(vc.x, vf);
      fp8x4_to_f32(vc.y, vf + 4);
#pragma unroll
      for (int jj = 0; jj < 8; ++jj) o[jj] = fmaf(ew, vf[jj], o[jj]);
      j += 8;
      kc = kn; vc = vn;
      kn = k2; vn = v2;
    }
  }

  __shared__ float o_sh[8][256];
  __shared__ float l_sh[8][8];
  *(float4*)&o_sh[stream][sl * 8]     = (float4){o[0], o[1], o[2], o[3]};
  *(float4*)&o_sh[stream][sl * 8 + 4] = (float4){o[4], o[5], o[6], o[7]};
  if ((sl & 3) == 0) l_sh[stream][sl >> 2] = lsum_p;
  __syncthreads();

  float osum = 0.f, lsum = 0.f;
  const int h = t >> 5;
#pragma unroll
  for (int s = 0; s < 8; ++s) {
    osum += o_sh[s][t];
    lsum += l_sh[s][h];
  }
  const float inv = 1.0f / fmaxf(lsum, 1e-8f);
  float res = 0.f;
  if (end > start) res = osum * inv + (lsum * inv) * bf2f(Gf[(size_t)q * 256 + t]);
  out_pre[(size_t)q * 256 + t] = f2bf(res);
}

extern "C" void kernel_launch(void* const* d_in, const int* in_sizes, int n_in,
                              void* d_out, int out_size, void* d_ws, size_t ws_size,
                              hipStream_t stream) {
  const float* query   = (const float*)d_in[0];
  const float* support = (const float*)d_in[1];
  const float* geo     = (const float*)d_in[2];
  const int*   q_idx   = (const int*)d_in[3];
  const int*   s_idx   = (const int*)d_in[4];
  const float* Wq      = (const float*)d_in[6];
  const float* Wk      = (const float*)d_in[7];
  const float* Wv      = (const float*)d_in[8];
  const float* Wg      = (const float*)d_in[9];
  const float* Wo      = (const float*)d_in[10];
  const float* bo      = (const float*)d_in[11];
  const float* log_tau = (const float*)d_in[12];

  const int D = 256;
  const int Q = in_sizes[0] / D;   // 8192
  const int N = in_sizes[1] / D;   // 65536
  const int E = in_sizes[3];       // 262144

  unsigned char* wsb = (unsigned char*)d_ws;
  unsigned char*  KV   = wsb;                                       // [N][512] fp8 K|V
  unsigned short* Qf   = (unsigned short*)(wsb + (size_t)N * 512);  // [Q][256]
  unsigned short* Gf   = Qf   + (size_t)Q * 256;   // [Q][256]
  unsigned short* Opre = Gf   + (size_t)Q * 256;   // [Q][256]
  unsigned short* Btkv = Opre + (size_t)Q * 256;   // [512][256] = [Wk^T; Wv^T]
  unsigned short* Btq  = Btkv + 512 * 256;         // [256][256]
  unsigned short* Btg  = Btq  + 256 * 256;         // [256][64]
  unsigned short* Bto  = Btg  + 256 * 64;          // [256][256]
  int* q_start = (int*)(Bto + 256 * 256);          // [Q+1]

  dim3 blk(256);

  prep<<<dim3(305), blk, 0, stream>>>(Wk, Wv, Wq, Wo, Wg,
                                      Btkv, Btq, Bto, Btg, q_idx, q_start, Q, E);

  // KV (persistent-A) + Qf + Gf projections in one dispatch
  proj<<<dim3(768), blk, 0, stream>>>(support, query, geo, Btkv, Btq, Btg,
                                      KV, Qf, Gf);

  edge_attn<<<dim3(Q), blk, 0, stream>>>(s_idx, q_start, KV,
                                         Qf, Gf, Opre, log_tau);

  gemm_final<<<dim3(128), blk, 0, stream>>>(Opre, Bto, d_out, bo);
}